// Round 1
// baseline (1983.122 us; speedup 1.0000x reference)
//
#include <hip/hip_runtime.h>

#define NN 50000
#define NE 400000
#define HID 768
#define NL 4

typedef short bf16x8_t __attribute__((ext_vector_type(8)));
typedef float f32x4_t __attribute__((ext_vector_type(4)));

__device__ __forceinline__ unsigned short f2bf(float f) {
  union { float f; unsigned int u; } c; c.f = f;
  unsigned int u = c.u;
  u += 0x7FFF + ((u >> 16) & 1);   // round-to-nearest-even
  return (unsigned short)(u >> 16);
}
__device__ __forceinline__ float bf2f(unsigned short s) {
  union { unsigned int u; float f; } c; c.u = ((unsigned int)s) << 16;
  return c.f;
}

// ---- zero deg + cursor ----
__global__ void k_zero2(int* __restrict__ a, int* __restrict__ b, int n) {
  int i = blockIdx.x * blockDim.x + threadIdx.x;
  if (i < n) { a[i] = 0; b[i] = 0; }
}

// ---- fp32 -> bf16 weight conversion ----
__global__ void k_cvt(const float* __restrict__ a, unsigned short* __restrict__ o, int n) {
  int i = blockIdx.x * blockDim.x + threadIdx.x;
  if (i < n) o[i] = f2bf(a[i]);
}

// ---- input projection: h = x @ Wp.T + bp  (x: [NN,8], Wp: [HID,8]) ----
__global__ __launch_bounds__(256) void k_inproj(const float* __restrict__ x,
                                                const float* __restrict__ Wp,
                                                const float* __restrict__ bp,
                                                unsigned short* __restrict__ h) {
  int n = blockIdx.x;
  __shared__ float xs[8];
  if (threadIdx.x < 8) xs[threadIdx.x] = x[n * 8 + threadIdx.x];
  __syncthreads();
  for (int j = threadIdx.x; j < HID; j += 256) {
    const float* w = Wp + j * 8;
    float s = bp[j];
#pragma unroll
    for (int k = 0; k < 8; ++k) s += xs[k] * w[k];
    h[(size_t)n * HID + j] = f2bf(s);
  }
}

// ---- degree count ----
__global__ void k_deg(const int* __restrict__ dst, int* __restrict__ deg) {
  int i = blockIdx.x * blockDim.x + threadIdx.x;
  if (i < NE) atomicAdd(&deg[dst[i]], 1);
}

// ---- exclusive scan over deg -> rowptr (single block) ----
__global__ __launch_bounds__(1024) void k_scan(const int* __restrict__ deg, int* __restrict__ rowptr) {
  __shared__ int sm[1024];
  const int chunk = 49;  // ceil(50000/1024)
  int t = threadIdx.x;
  int start = t * chunk;
  int end = min(start + chunk, NN);
  int local = 0;
  for (int i = start; i < end; ++i) local += deg[i];
  sm[t] = local;
  __syncthreads();
  for (int off = 1; off < 1024; off <<= 1) {
    int v = (t >= off) ? sm[t - off] : 0;
    __syncthreads();
    sm[t] += v;
    __syncthreads();
  }
  int run = sm[t] - local;  // exclusive prefix
  for (int i = start; i < end; ++i) { rowptr[i] = run; run += deg[i]; }
  if (start < NN && end == NN) rowptr[NN] = run;
}

// ---- CSR fill ----
__global__ void k_fill(const int* __restrict__ src, const int* __restrict__ dst,
                       const int* __restrict__ rowptr, int* __restrict__ cursor,
                       int* __restrict__ csr) {
  int i = blockIdx.x * blockDim.x + threadIdx.x;
  if (i < NE) {
    int d = dst[i];
    int pos = atomicAdd(&cursor[d], 1);
    csr[rowptr[d] + pos] = src[i];
  }
}

// ---- mean aggregation: agg[n] = mean over neighbors of h[src] ----
__global__ __launch_bounds__(192) void k_agg(const unsigned short* __restrict__ h,
                                             const int* __restrict__ csr,
                                             const int* __restrict__ rowptr,
                                             unsigned short* __restrict__ agg) {
  int n = blockIdx.x;
  int t = threadIdx.x;
  int beg = rowptr[n], end = rowptr[n + 1];
  float a0 = 0.f, a1 = 0.f, a2 = 0.f, a3 = 0.f;
  for (int i = beg; i < end; ++i) {
    int s = csr[i];
    ushort4 v = *(const ushort4*)(h + (size_t)s * HID + t * 4);
    a0 += bf2f(v.x); a1 += bf2f(v.y); a2 += bf2f(v.z); a3 += bf2f(v.w);
  }
  float inv = 1.0f / (float)max(end - beg, 1);
  ushort4 o;
  o.x = f2bf(a0 * inv); o.y = f2bf(a1 * inv); o.z = f2bf(a2 * inv); o.w = f2bf(a3 * inv);
  *(ushort4*)(agg + (size_t)n * HID + t * 4) = o;
}

// ---- fused GEMM: pre = agg@Wl.T + h@Wr.T + bl   (bf16 MFMA, fp32 out) ----
#define BM 128
#define BN 128
#define BK 32
#define LST 40  // padded LDS row stride in bf16 elems

__global__ __launch_bounds__(256) void k_gemm(const unsigned short* __restrict__ A0,  // agg
                                              const unsigned short* __restrict__ A1,  // h
                                              const unsigned short* __restrict__ B0,  // Wl (bf16, [j,k])
                                              const unsigned short* __restrict__ B1,  // Wr
                                              const float* __restrict__ bias,
                                              float* __restrict__ out, int M) {
  __shared__ unsigned short As[BM * LST];
  __shared__ unsigned short Bs[BN * LST];
  f32x4_t acc[4][4] = {};
  int m0 = blockIdx.x * BM;
  int n0 = blockIdx.y * BN;
  int tid = threadIdx.x;
  int lane = tid & 63, w = tid >> 6;
  int wr = w >> 1, wc = w & 1;
  int srow = tid >> 2;          // 0..63
  int scol = (tid & 3) * 8;     // 0,8,16,24

  for (int phase = 0; phase < 2; ++phase) {
    const unsigned short* A = phase ? A1 : A0;
    const unsigned short* B = phase ? B1 : B0;
    for (int k0 = 0; k0 < HID; k0 += BK) {
      __syncthreads();
#pragma unroll
      for (int p = 0; p < 2; ++p) {
        int row = p * 64 + srow;
        int gm = m0 + row;
        int4 va;
        if (gm < M) va = *(const int4*)(A + (size_t)gm * HID + k0 + scol);
        else        va = int4{0, 0, 0, 0};
        *(int4*)(&As[row * LST + scol]) = va;
        int4 vb = *(const int4*)(B + (size_t)(n0 + row) * HID + k0 + scol);
        *(int4*)(&Bs[row * LST + scol]) = vb;
      }
      __syncthreads();
      bf16x8_t af[4], bf[4];
      int kq = (lane >> 4) * 8;
      int mr = lane & 15;
#pragma unroll
      for (int t = 0; t < 4; ++t) {
        af[t] = *(const bf16x8_t*)(&As[(wr * 64 + t * 16 + mr) * LST + kq]);
        bf[t] = *(const bf16x8_t*)(&Bs[(wc * 64 + t * 16 + mr) * LST + kq]);
      }
#pragma unroll
      for (int mt = 0; mt < 4; ++mt)
#pragma unroll
        for (int nt = 0; nt < 4; ++nt)
          acc[mt][nt] = __builtin_amdgcn_mfma_f32_16x16x32_bf16(af[mt], bf[nt], acc[mt][nt], 0, 0, 0);
    }
  }
  // epilogue: C(row=(lane>>4)*4+r, col=lane&15) per 16x16 tile
  int col = lane & 15;
  int rq = (lane >> 4) * 4;
#pragma unroll
  for (int mt = 0; mt < 4; ++mt) {
#pragma unroll
    for (int nt = 0; nt < 4; ++nt) {
      int j = n0 + wc * 64 + nt * 16 + col;
      float b = bias[j];
#pragma unroll
      for (int r = 0; r < 4; ++r) {
        int gm = m0 + wr * 64 + mt * 16 + rq + r;
        if (gm < M) out[(size_t)gm * HID + j] = acc[mt][nt][r] + b;
      }
    }
  }
}

// ---- silu + LayerNorm; write bf16 h (next layer) or fp32 final out ----
__global__ __launch_bounds__(256) void k_siluln(const float* __restrict__ pre,
                                                const float* __restrict__ gamma,
                                                const float* __restrict__ beta,
                                                unsigned short* __restrict__ hout,
                                                float* __restrict__ fout) {
  int n = blockIdx.x;
  const float* p = pre + (size_t)n * HID;
  float v[3];
  float sum = 0.f, sq = 0.f;
#pragma unroll
  for (int i = 0; i < 3; ++i) {
    float x = p[threadIdx.x + i * 256];
    float s = x / (1.f + __expf(-x));
    v[i] = s; sum += s; sq += s * s;
  }
#pragma unroll
  for (int off = 32; off >= 1; off >>= 1) {
    sum += __shfl_down(sum, off);
    sq  += __shfl_down(sq, off);
  }
  __shared__ float rs[4], rq2[4];
  int wv = threadIdx.x >> 6;
  if ((threadIdx.x & 63) == 0) { rs[wv] = sum; rq2[wv] = sq; }
  __syncthreads();
  if (threadIdx.x == 0) {
    float s = rs[0] + rs[1] + rs[2] + rs[3];
    float q = rq2[0] + rq2[1] + rq2[2] + rq2[3];
    rs[0] = s / (float)HID;
    rq2[0] = q / (float)HID;
  }
  __syncthreads();
  float mu = rs[0];
  float var = rq2[0] - mu * mu;
  float inv = rsqrtf(var + 1e-5f);
#pragma unroll
  for (int i = 0; i < 3; ++i) {
    int j = threadIdx.x + i * 256;
    float y = (v[i] - mu) * inv * gamma[j] + beta[j];
    if (fout) fout[(size_t)n * HID + j] = y;
    else      hout[(size_t)n * HID + j] = f2bf(y);
  }
}

extern "C" void kernel_launch(void* const* d_in, const int* in_sizes, int n_in,
                              void* d_out, int out_size, void* d_ws, size_t ws_size,
                              hipStream_t stream) {
  const float* x     = (const float*)d_in[0];
  const float* Wp    = (const float*)d_in[1];
  const float* bp    = (const float*)d_in[2];
  const float* Wl    = (const float*)d_in[3];
  const float* bl    = (const float*)d_in[4];
  const float* Wr    = (const float*)d_in[5];
  const float* gamma = (const float*)d_in[6];
  const float* beta  = (const float*)d_in[7];
  const int*   ei    = (const int*)d_in[8];
  float* out = (float*)d_out;

  const int* src = ei;
  const int* dst = ei + NE;

  // workspace carve (all offsets 16B-aligned)
  char* p = (char*)d_ws;
  unsigned short* h    = (unsigned short*)p;              p += (size_t)NN * HID * 2;  // 76.8 MB
  unsigned short* agg  = (unsigned short*)p;              p += (size_t)NN * HID * 2;  // 76.8 MB
  float* pre           = (float*)p;                       p += (size_t)NN * HID * 4;  // 153.6 MB
  unsigned short* Wlb  = (unsigned short*)p;              p += (size_t)NL * HID * HID * 2;
  unsigned short* Wrb  = (unsigned short*)p;              p += (size_t)NL * HID * HID * 2;
  int* deg             = (int*)p;                         p += (size_t)NN * 4;
  int* rowptr          = (int*)p;                         p += (size_t)(NN + 1) * 4 + 12;
  int* cursor          = (int*)p;                         p += (size_t)NN * 4;
  int* csr             = (int*)p;                         p += (size_t)NE * 4;

  // graph build + weight prep
  k_zero2<<<(NN + 255) / 256, 256, 0, stream>>>(deg, cursor, NN);
  int wn = NL * HID * HID;
  k_cvt<<<(wn + 255) / 256, 256, 0, stream>>>(Wl, Wlb, wn);
  k_cvt<<<(wn + 255) / 256, 256, 0, stream>>>(Wr, Wrb, wn);
  k_inproj<<<NN, 256, 0, stream>>>(x, Wp, bp, h);
  k_deg<<<(NE + 255) / 256, 256, 0, stream>>>(dst, deg);
  k_scan<<<1, 1024, 0, stream>>>(deg, rowptr);
  k_fill<<<(NE + 255) / 256, 256, 0, stream>>>(src, dst, rowptr, cursor, csr);

  dim3 ggrid((NN + BM - 1) / BM, HID / BN);
  for (int l = 0; l < NL; ++l) {
    k_agg<<<NN, 192, 0, stream>>>(h, csr, rowptr, agg);
    k_gemm<<<ggrid, 256, 0, stream>>>(agg, h,
                                      Wlb + (size_t)l * HID * HID,
                                      Wrb + (size_t)l * HID * HID,
                                      bl + (size_t)l * HID, pre, NN);
    k_siluln<<<NN, 256, 0, stream>>>(pre, gamma + (size_t)l * HID, beta + (size_t)l * HID,
                                     h, (l == NL - 1) ? out : nullptr);
  }
}

// Round 2
// 1793.939 us; speedup vs baseline: 1.1055x; 1.1055x over previous
//
#include <hip/hip_runtime.h>

#define NN 50000
#define NE 400000
#define HID 768
#define NL 4

typedef short bf16x8_t __attribute__((ext_vector_type(8)));
typedef float f32x4_t __attribute__((ext_vector_type(4)));

__device__ __forceinline__ unsigned short f2bf(float f) {
  union { float f; unsigned int u; } c; c.f = f;
  unsigned int u = c.u;
  u += 0x7FFF + ((u >> 16) & 1);   // round-to-nearest-even
  return (unsigned short)(u >> 16);
}
__device__ __forceinline__ float bf2f(unsigned short s) {
  union { unsigned int u; float f; } c; c.u = ((unsigned int)s) << 16;
  return c.f;
}

// async global->LDS, 16B per lane; LDS dest = base + lane*16 (wave-uniform base)
__device__ __forceinline__ void async16(const void* g, void* l) {
  __builtin_amdgcn_global_load_lds((const __attribute__((address_space(1))) void*)g,
                                   (__attribute__((address_space(3))) void*)l,
                                   16, 0, 0);
}

// ---- zero deg + cursor ----
__global__ void k_zero2(int* __restrict__ a, int* __restrict__ b, int n) {
  int i = blockIdx.x * blockDim.x + threadIdx.x;
  if (i < n) { a[i] = 0; b[i] = 0; }
}

// ---- fp32 -> bf16 weight conversion ----
__global__ void k_cvt(const float* __restrict__ a, unsigned short* __restrict__ o, int n) {
  int i = blockIdx.x * blockDim.x + threadIdx.x;
  if (i < n) o[i] = f2bf(a[i]);
}

// ---- input projection: h = x @ Wp.T + bp  (x: [NN,8], Wp: [HID,8]) ----
__global__ __launch_bounds__(256) void k_inproj(const float* __restrict__ x,
                                                const float* __restrict__ Wp,
                                                const float* __restrict__ bp,
                                                unsigned short* __restrict__ h) {
  int n = blockIdx.x;
  __shared__ float xs[8];
  if (threadIdx.x < 8) xs[threadIdx.x] = x[n * 8 + threadIdx.x];
  __syncthreads();
  for (int j = threadIdx.x; j < HID; j += 256) {
    const float* w = Wp + j * 8;
    float s = bp[j];
#pragma unroll
    for (int k = 0; k < 8; ++k) s += xs[k] * w[k];
    h[(size_t)n * HID + j] = f2bf(s);
  }
}

// ---- degree count ----
__global__ void k_deg(const int* __restrict__ dst, int* __restrict__ deg) {
  int i = blockIdx.x * blockDim.x + threadIdx.x;
  if (i < NE) atomicAdd(&deg[dst[i]], 1);
}

// ---- exclusive scan over deg -> rowptr (single block) ----
__global__ __launch_bounds__(1024) void k_scan(const int* __restrict__ deg, int* __restrict__ rowptr) {
  __shared__ int sm[1024];
  const int chunk = 49;  // ceil(50000/1024)
  int t = threadIdx.x;
  int start = t * chunk;
  int end = min(start + chunk, NN);
  int local = 0;
  for (int i = start; i < end; ++i) local += deg[i];
  sm[t] = local;
  __syncthreads();
  for (int off = 1; off < 1024; off <<= 1) {
    int v = (t >= off) ? sm[t - off] : 0;
    __syncthreads();
    sm[t] += v;
    __syncthreads();
  }
  int run = sm[t] - local;  // exclusive prefix
  for (int i = start; i < end; ++i) { rowptr[i] = run; run += deg[i]; }
  if (start < NN && end == NN) rowptr[NN] = run;
}

// ---- CSR fill ----
__global__ void k_fill(const int* __restrict__ src, const int* __restrict__ dst,
                       const int* __restrict__ rowptr, int* __restrict__ cursor,
                       int* __restrict__ csr) {
  int i = blockIdx.x * blockDim.x + threadIdx.x;
  if (i < NE) {
    int d = dst[i];
    int pos = atomicAdd(&cursor[d], 1);
    csr[rowptr[d] + pos] = src[i];
  }
}

// ---- mean aggregation: agg[n] = mean over neighbors of h[src] ----
__global__ __launch_bounds__(192) void k_agg(const unsigned short* __restrict__ h,
                                             const int* __restrict__ csr,
                                             const int* __restrict__ rowptr,
                                             unsigned short* __restrict__ agg) {
  int n = blockIdx.x;
  int t = threadIdx.x;
  int beg = rowptr[n], end = rowptr[n + 1];
  float a0 = 0.f, a1 = 0.f, a2 = 0.f, a3 = 0.f;
  for (int i = beg; i < end; ++i) {
    int s = csr[i];
    ushort4 v = *(const ushort4*)(h + (size_t)s * HID + t * 4);
    a0 += bf2f(v.x); a1 += bf2f(v.y); a2 += bf2f(v.z); a3 += bf2f(v.w);
  }
  float inv = 1.0f / (float)max(end - beg, 1);
  ushort4 o;
  o.x = f2bf(a0 * inv); o.y = f2bf(a1 * inv); o.z = f2bf(a2 * inv); o.w = f2bf(a3 * inv);
  *(ushort4*)(agg + (size_t)n * HID + t * 4) = o;
}

// ---- fused GEMM: sact = silu(agg@Wl.T + h@Wr.T + bl)  (bf16 MFMA, bf16 out)
// grid (x = N tiles = 6, y = M tiles = 391) so consecutive blocks share one
// A row-band -> A fetched ~once from HBM.
// Staging via global_load_lds width=16 (m97 pattern): LDS rows unpadded 64B.
#define BM 128
#define BN 128
#define BK 32

__global__ __launch_bounds__(256) void k_gemm(const unsigned short* __restrict__ A0,  // agg
                                              const unsigned short* __restrict__ A1,  // h
                                              const unsigned short* __restrict__ B0,  // Wl (bf16, [j,k])
                                              const unsigned short* __restrict__ B1,  // Wr
                                              const float* __restrict__ bias,
                                              unsigned short* __restrict__ sact, int M) {
  __shared__ unsigned short As[BM * BK];
  __shared__ unsigned short Bs[BN * BK];
  f32x4_t acc[4][4] = {};
  int n0 = blockIdx.x * BN;
  int m0 = blockIdx.y * BM;
  int tid = threadIdx.x;
  int lane = tid & 63, w = tid >> 6;
  int wr = w >> 1, wc = w & 1;
  int r4 = lane >> 2;           // 0..15 (row within 16-row DMA segment)
  int cs = (lane & 3) * 8;      // elem offset within 32-elem row

  for (int phase = 0; phase < 2; ++phase) {
    const unsigned short* A = phase ? A1 : A0;
    const unsigned short* B = phase ? B1 : B0;
    for (int k0 = 0; k0 < HID; k0 += BK) {
      __syncthreads();  // previous consume finished before overwrite
#pragma unroll
      for (int c = 0; c < 2; ++c) {
        int seg = w * 32 + c * 16;          // first row of this 16-row segment
        int row = seg + r4;
        async16(A + (size_t)(m0 + row) * HID + k0 + cs, &As[seg * BK]);
        async16(B + (size_t)(n0 + row) * HID + k0 + cs, &Bs[seg * BK]);
      }
      __syncthreads();  // drains vmcnt -> LDS tiles ready
      bf16x8_t af[4], bfr[4];
      int kq = (lane >> 4) * 8;
      int mr = lane & 15;
#pragma unroll
      for (int t = 0; t < 4; ++t) {
        af[t]  = *(const bf16x8_t*)(&As[(wr * 64 + t * 16 + mr) * BK + kq]);
        bfr[t] = *(const bf16x8_t*)(&Bs[(wc * 64 + t * 16 + mr) * BK + kq]);
      }
#pragma unroll
      for (int mt = 0; mt < 4; ++mt)
#pragma unroll
        for (int nt = 0; nt < 4; ++nt)
          acc[mt][nt] = __builtin_amdgcn_mfma_f32_16x16x32_bf16(af[mt], bfr[nt], acc[mt][nt], 0, 0, 0);
    }
  }
  // epilogue: C(row=(lane>>4)*4+r, col=lane&15); fuse bias + silu, store bf16
  int col = lane & 15;
  int rq = (lane >> 4) * 4;
#pragma unroll
  for (int mt = 0; mt < 4; ++mt) {
#pragma unroll
    for (int nt = 0; nt < 4; ++nt) {
      int j = n0 + wc * 64 + nt * 16 + col;
      float b = bias[j];
#pragma unroll
      for (int r = 0; r < 4; ++r) {
        int gm = m0 + wr * 64 + mt * 16 + rq + r;
        if (gm < M) {
          float v = acc[mt][nt][r] + b;
          float s = v / (1.f + __expf(-v));
          sact[(size_t)gm * HID + j] = f2bf(s);
        }
      }
    }
  }
}

// ---- LayerNorm over bf16 silu activations; write bf16 h or fp32 final out ----
__global__ __launch_bounds__(256) void k_ln(const unsigned short* __restrict__ sact,
                                            const float* __restrict__ gamma,
                                            const float* __restrict__ beta,
                                            unsigned short* __restrict__ hout,
                                            float* __restrict__ fout) {
  int n = blockIdx.x;
  const unsigned short* p = sact + (size_t)n * HID;
  float v[3];
  float sum = 0.f, sq = 0.f;
#pragma unroll
  for (int i = 0; i < 3; ++i) {
    float s = bf2f(p[threadIdx.x + i * 256]);
    v[i] = s; sum += s; sq += s * s;
  }
#pragma unroll
  for (int off = 32; off >= 1; off >>= 1) {
    sum += __shfl_down(sum, off);
    sq  += __shfl_down(sq, off);
  }
  __shared__ float rs[4], rq2[4];
  int wv = threadIdx.x >> 6;
  if ((threadIdx.x & 63) == 0) { rs[wv] = sum; rq2[wv] = sq; }
  __syncthreads();
  if (threadIdx.x == 0) {
    float s = rs[0] + rs[1] + rs[2] + rs[3];
    float q = rq2[0] + rq2[1] + rq2[2] + rq2[3];
    rs[0] = s / (float)HID;
    rq2[0] = q / (float)HID;
  }
  __syncthreads();
  float mu = rs[0];
  float var = rq2[0] - mu * mu;
  float inv = rsqrtf(var + 1e-5f);
#pragma unroll
  for (int i = 0; i < 3; ++i) {
    int j = threadIdx.x + i * 256;
    float y = (v[i] - mu) * inv * gamma[j] + beta[j];
    if (fout) fout[(size_t)n * HID + j] = y;
    else      hout[(size_t)n * HID + j] = f2bf(y);
  }
}

extern "C" void kernel_launch(void* const* d_in, const int* in_sizes, int n_in,
                              void* d_out, int out_size, void* d_ws, size_t ws_size,
                              hipStream_t stream) {
  const float* x     = (const float*)d_in[0];
  const float* Wp    = (const float*)d_in[1];
  const float* bp    = (const float*)d_in[2];
  const float* Wl    = (const float*)d_in[3];
  const float* bl    = (const float*)d_in[4];
  const float* Wr    = (const float*)d_in[5];
  const float* gamma = (const float*)d_in[6];
  const float* beta  = (const float*)d_in[7];
  const int*   ei    = (const int*)d_in[8];
  float* out = (float*)d_out;

  const int* src = ei;
  const int* dst = ei + NE;

  // workspace carve (all offsets 16B-aligned).
  // NOTE: k_gemm loads A rows up to m0+127 (<= 50047) unconditionally; rows
  // >= NN read into the NEXT buffer in this carve — allocated, harmless
  // (results masked on store). Keep h, agg, sact adjacent and in this order.
  char* p = (char*)d_ws;
  unsigned short* h    = (unsigned short*)p;              p += (size_t)NN * HID * 2;  // 76.8 MB
  unsigned short* agg  = (unsigned short*)p;              p += (size_t)NN * HID * 2;  // 76.8 MB
  unsigned short* sact = (unsigned short*)p;              p += (size_t)NN * HID * 2;  // 76.8 MB
  unsigned short* Wlb  = (unsigned short*)p;              p += (size_t)NL * HID * HID * 2;
  unsigned short* Wrb  = (unsigned short*)p;              p += (size_t)NL * HID * HID * 2;
  int* deg             = (int*)p;                         p += (size_t)NN * 4;
  int* rowptr          = (int*)p;                         p += (size_t)(NN + 1) * 4 + 12;
  int* cursor          = (int*)p;                         p += (size_t)NN * 4;
  int* csr             = (int*)p;                         p += (size_t)NE * 4;

  // graph build + weight prep
  k_zero2<<<(NN + 255) / 256, 256, 0, stream>>>(deg, cursor, NN);
  int wn = NL * HID * HID;
  k_cvt<<<(wn + 255) / 256, 256, 0, stream>>>(Wl, Wlb, wn);
  k_cvt<<<(wn + 255) / 256, 256, 0, stream>>>(Wr, Wrb, wn);
  k_inproj<<<NN, 256, 0, stream>>>(x, Wp, bp, h);
  k_deg<<<(NE + 255) / 256, 256, 0, stream>>>(dst, deg);
  k_scan<<<1, 1024, 0, stream>>>(deg, rowptr);
  k_fill<<<(NE + 255) / 256, 256, 0, stream>>>(src, dst, rowptr, cursor, csr);

  dim3 ggrid(HID / BN, (NN + BM - 1) / BM);  // x = N tiles (6), y = M tiles (391)
  for (int l = 0; l < NL; ++l) {
    k_agg<<<NN, 192, 0, stream>>>(h, csr, rowptr, agg);
    k_gemm<<<ggrid, 256, 0, stream>>>(agg, h,
                                      Wlb + (size_t)l * HID * HID,
                                      Wrb + (size_t)l * HID * HID,
                                      bl + (size_t)l * HID, sact, NN);
    k_ln<<<NN, 256, 0, stream>>>(sact, gamma + (size_t)l * HID, beta + (size_t)l * HID,
                                 h, (l == NL - 1) ? out : nullptr);
  }
}

// Round 3
// 1701.150 us; speedup vs baseline: 1.1658x; 1.0545x over previous
//
#include <hip/hip_runtime.h>

#define NN 50000
#define NE 400000
#define HID 768
#define NL 4

typedef short bf16x8_t __attribute__((ext_vector_type(8)));
typedef float f32x4_t __attribute__((ext_vector_type(4)));

__device__ __forceinline__ unsigned short f2bf(float f) {
  union { float f; unsigned int u; } c; c.f = f;
  unsigned int u = c.u;
  u += 0x7FFF + ((u >> 16) & 1);   // round-to-nearest-even
  return (unsigned short)(u >> 16);
}
__device__ __forceinline__ float bf2f(unsigned short s) {
  union { unsigned int u; float f; } c; c.u = ((unsigned int)s) << 16;
  return c.f;
}

// async global->LDS, 16B per lane; LDS dest = base + lane*16 (wave-uniform base)
__device__ __forceinline__ void async16(const void* g, void* l) {
  __builtin_amdgcn_global_load_lds((const __attribute__((address_space(1))) void*)g,
                                   (__attribute__((address_space(3))) void*)l,
                                   16, 0, 0);
}

// ---- zero deg + cursor ----
__global__ void k_zero2(int* __restrict__ a, int* __restrict__ b, int n) {
  int i = blockIdx.x * blockDim.x + threadIdx.x;
  if (i < n) { a[i] = 0; b[i] = 0; }
}

// ---- fp32 -> bf16 weight conversion ----
__global__ void k_cvt(const float* __restrict__ a, unsigned short* __restrict__ o, int n) {
  int i = blockIdx.x * blockDim.x + threadIdx.x;
  if (i < n) o[i] = f2bf(a[i]);
}

// ---- input projection: h = x @ Wp.T + bp  (x: [NN,8], Wp: [HID,8]) ----
__global__ __launch_bounds__(256) void k_inproj(const float* __restrict__ x,
                                                const float* __restrict__ Wp,
                                                const float* __restrict__ bp,
                                                unsigned short* __restrict__ h) {
  int n = blockIdx.x;
  __shared__ float xs[8];
  if (threadIdx.x < 8) xs[threadIdx.x] = x[n * 8 + threadIdx.x];
  __syncthreads();
  for (int j = threadIdx.x; j < HID; j += 256) {
    const float* w = Wp + j * 8;
    float s = bp[j];
#pragma unroll
    for (int k = 0; k < 8; ++k) s += xs[k] * w[k];
    h[(size_t)n * HID + j] = f2bf(s);
  }
}

// ---- degree count ----
__global__ void k_deg(const int* __restrict__ dst, int* __restrict__ deg) {
  int i = blockIdx.x * blockDim.x + threadIdx.x;
  if (i < NE) atomicAdd(&deg[dst[i]], 1);
}

// ---- exclusive scan over deg -> rowptr (single block) ----
__global__ __launch_bounds__(1024) void k_scan(const int* __restrict__ deg, int* __restrict__ rowptr) {
  __shared__ int sm[1024];
  const int chunk = 49;  // ceil(50000/1024)
  int t = threadIdx.x;
  int start = t * chunk;
  int end = min(start + chunk, NN);
  int local = 0;
  for (int i = start; i < end; ++i) local += deg[i];
  sm[t] = local;
  __syncthreads();
  for (int off = 1; off < 1024; off <<= 1) {
    int v = (t >= off) ? sm[t - off] : 0;
    __syncthreads();
    sm[t] += v;
    __syncthreads();
  }
  int run = sm[t] - local;  // exclusive prefix
  for (int i = start; i < end; ++i) { rowptr[i] = run; run += deg[i]; }
  if (start < NN && end == NN) rowptr[NN] = run;
}

// ---- CSR fill ----
__global__ void k_fill(const int* __restrict__ src, const int* __restrict__ dst,
                       const int* __restrict__ rowptr, int* __restrict__ cursor,
                       int* __restrict__ csr) {
  int i = blockIdx.x * blockDim.x + threadIdx.x;
  if (i < NE) {
    int d = dst[i];
    int pos = atomicAdd(&cursor[d], 1);
    csr[rowptr[d] + pos] = src[i];
  }
}

// ---- mean aggregation: agg[n] = mean over neighbors of h[src] ----
__global__ __launch_bounds__(192) void k_agg(const unsigned short* __restrict__ h,
                                             const int* __restrict__ csr,
                                             const int* __restrict__ rowptr,
                                             unsigned short* __restrict__ agg) {
  int n = blockIdx.x;
  int t = threadIdx.x;
  int beg = rowptr[n], end = rowptr[n + 1];
  float a0 = 0.f, a1 = 0.f, a2 = 0.f, a3 = 0.f;
  for (int i = beg; i < end; ++i) {
    int s = csr[i];
    ushort4 v = *(const ushort4*)(h + (size_t)s * HID + t * 4);
    a0 += bf2f(v.x); a1 += bf2f(v.y); a2 += bf2f(v.z); a3 += bf2f(v.w);
  }
  float inv = 1.0f / (float)max(end - beg, 1);
  ushort4 o;
  o.x = f2bf(a0 * inv); o.y = f2bf(a1 * inv); o.z = f2bf(a2 * inv); o.w = f2bf(a3 * inv);
  *(ushort4*)(agg + (size_t)n * HID + t * 4) = o;
}

// ---- fused GEMM: sact = silu(agg@Wl.T + h@Wr.T + bl)  (bf16 MFMA, bf16 out)
// Grid: 1-D, 8*6*49 = 2352 blocks. Decode puts all 6 N-tiles of one M band on
// the SAME XCD (blockIdx%8 round-robin assumption) so A tiles hit that XCD's
// L2 instead of being re-fetched by up to 6 XCDs (R2: FETCH 473MB ~ 3x ideal).
// LDS layout XOR-swizzled: stage-time colgroup' = colgroup ^ ((row>>1)&3),
// turning the 8-way ds_read_b128 bank conflict (R2: 1.44e7) into free 2-way.
#define BM 128
#define BN 128
#define BK 32
#define NBAND 391   // ceil(NN/BM)

__global__ __launch_bounds__(256) void k_gemm(const unsigned short* __restrict__ A0,  // agg
                                              const unsigned short* __restrict__ A1,  // h
                                              const unsigned short* __restrict__ B0,  // Wl (bf16, [j,k])
                                              const unsigned short* __restrict__ B1,  // Wr
                                              const float* __restrict__ bias,
                                              unsigned short* __restrict__ sact, int M) {
  int b = blockIdx.x;
  int xcd = b & 7;
  int rest = b >> 3;
  int nt6 = rest % 6;
  int g = rest / 6;
  int mband = g * 8 + xcd;
  if (mband >= NBAND) return;
  int m0 = mband * BM;
  int n0 = nt6 * BN;

  __shared__ unsigned short As[BM * BK];
  __shared__ unsigned short Bs[BN * BK];
  f32x4_t acc[4][4] = {};
  int tid = threadIdx.x;
  int lane = tid & 63, w = tid >> 6;
  int wr = w >> 1, wc = w & 1;
  int r4 = lane >> 2;                       // 0..15 (row within 16-row DMA segment)
  int cg = (lane & 3) ^ ((lane >> 3) & 3);  // swizzled col-group (16B units)
  int cs = cg * 8;                          // elem offset within 32-elem row

  for (int phase = 0; phase < 2; ++phase) {
    const unsigned short* A = phase ? A1 : A0;
    const unsigned short* B = phase ? B1 : B0;
    for (int k0 = 0; k0 < HID; k0 += BK) {
      __syncthreads();  // previous consume finished before overwrite
#pragma unroll
      for (int c = 0; c < 2; ++c) {
        int seg = w * 32 + c * 16;          // first row of this 16-row segment
        int row = seg + r4;
        async16(A + (size_t)(m0 + row) * HID + k0 + cs, &As[seg * BK]);
        async16(B + (size_t)(n0 + row) * HID + k0 + cs, &Bs[seg * BK]);
      }
      __syncthreads();  // drains vmcnt -> LDS tiles ready
      bf16x8_t af[4], bfr[4];
      int q = lane >> 4;                    // col-group wanted (0..3)
      int mr = lane & 15;
      int sq = (q ^ ((mr >> 1) & 3)) * 8;   // swizzled elem offset
#pragma unroll
      for (int t = 0; t < 4; ++t) {
        af[t]  = *(const bf16x8_t*)(&As[(wr * 64 + t * 16 + mr) * BK + sq]);
        bfr[t] = *(const bf16x8_t*)(&Bs[(wc * 64 + t * 16 + mr) * BK + sq]);
      }
#pragma unroll
      for (int mt = 0; mt < 4; ++mt)
#pragma unroll
        for (int nt = 0; nt < 4; ++nt)
          acc[mt][nt] = __builtin_amdgcn_mfma_f32_16x16x32_bf16(af[mt], bfr[nt], acc[mt][nt], 0, 0, 0);
    }
  }
  // epilogue: C(row=(lane>>4)*4+r, col=lane&15); fuse bias + silu, store bf16
  int col = lane & 15;
  int rq = (lane >> 4) * 4;
#pragma unroll
  for (int mt = 0; mt < 4; ++mt) {
#pragma unroll
    for (int nt = 0; nt < 4; ++nt) {
      int j = n0 + wc * 64 + nt * 16 + col;
      float bv = bias[j];
#pragma unroll
      for (int r = 0; r < 4; ++r) {
        int gm = m0 + wr * 64 + mt * 16 + rq + r;
        if (gm < M) {
          float v = acc[mt][nt][r] + bv;
          float s = v / (1.f + __expf(-v));
          sact[(size_t)gm * HID + j] = f2bf(s);
        }
      }
    }
  }
}

// ---- LayerNorm over bf16 silu activations; write bf16 h or fp32 final out ----
__global__ __launch_bounds__(256) void k_ln(const unsigned short* __restrict__ sact,
                                            const float* __restrict__ gamma,
                                            const float* __restrict__ beta,
                                            unsigned short* __restrict__ hout,
                                            float* __restrict__ fout) {
  int n = blockIdx.x;
  const unsigned short* p = sact + (size_t)n * HID;
  float v[3];
  float sum = 0.f, sq = 0.f;
#pragma unroll
  for (int i = 0; i < 3; ++i) {
    float s = bf2f(p[threadIdx.x + i * 256]);
    v[i] = s; sum += s; sq += s * s;
  }
#pragma unroll
  for (int off = 32; off >= 1; off >>= 1) {
    sum += __shfl_down(sum, off);
    sq  += __shfl_down(sq, off);
  }
  __shared__ float rs[4], rq2[4];
  int wv = threadIdx.x >> 6;
  if ((threadIdx.x & 63) == 0) { rs[wv] = sum; rq2[wv] = sq; }
  __syncthreads();
  if (threadIdx.x == 0) {
    float s = rs[0] + rs[1] + rs[2] + rs[3];
    float q = rq2[0] + rq2[1] + rq2[2] + rq2[3];
    rs[0] = s / (float)HID;
    rq2[0] = q / (float)HID;
  }
  __syncthreads();
  float mu = rs[0];
  float var = rq2[0] - mu * mu;
  float inv = rsqrtf(var + 1e-5f);
#pragma unroll
  for (int i = 0; i < 3; ++i) {
    int j = threadIdx.x + i * 256;
    float y = (v[i] - mu) * inv * gamma[j] + beta[j];
    if (fout) fout[(size_t)n * HID + j] = y;
    else      hout[(size_t)n * HID + j] = f2bf(y);
  }
}

extern "C" void kernel_launch(void* const* d_in, const int* in_sizes, int n_in,
                              void* d_out, int out_size, void* d_ws, size_t ws_size,
                              hipStream_t stream) {
  const float* x     = (const float*)d_in[0];
  const float* Wp    = (const float*)d_in[1];
  const float* bp    = (const float*)d_in[2];
  const float* Wl    = (const float*)d_in[3];
  const float* bl    = (const float*)d_in[4];
  const float* Wr    = (const float*)d_in[5];
  const float* gamma = (const float*)d_in[6];
  const float* beta  = (const float*)d_in[7];
  const int*   ei    = (const int*)d_in[8];
  float* out = (float*)d_out;

  const int* src = ei;
  const int* dst = ei + NE;

  // workspace carve (all offsets 16B-aligned).
  // NOTE: k_gemm loads A rows up to m0+127 (<= 50047) unconditionally; rows
  // >= NN read into the NEXT buffer in this carve — allocated, harmless
  // (results masked on store). Keep h, agg, sact adjacent and in this order.
  char* p = (char*)d_ws;
  unsigned short* h    = (unsigned short*)p;              p += (size_t)NN * HID * 2;  // 76.8 MB
  unsigned short* agg  = (unsigned short*)p;              p += (size_t)NN * HID * 2;  // 76.8 MB
  unsigned short* sact = (unsigned short*)p;              p += (size_t)NN * HID * 2;  // 76.8 MB
  unsigned short* Wlb  = (unsigned short*)p;              p += (size_t)NL * HID * HID * 2;
  unsigned short* Wrb  = (unsigned short*)p;              p += (size_t)NL * HID * HID * 2;
  int* deg             = (int*)p;                         p += (size_t)NN * 4;
  int* rowptr          = (int*)p;                         p += (size_t)(NN + 1) * 4 + 12;
  int* cursor          = (int*)p;                         p += (size_t)NN * 4;
  int* csr             = (int*)p;                         p += (size_t)NE * 4;

  // graph build + weight prep
  k_zero2<<<(NN + 255) / 256, 256, 0, stream>>>(deg, cursor, NN);
  int wn = NL * HID * HID;
  k_cvt<<<(wn + 255) / 256, 256, 0, stream>>>(Wl, Wlb, wn);
  k_cvt<<<(wn + 255) / 256, 256, 0, stream>>>(Wr, Wrb, wn);
  k_inproj<<<NN, 256, 0, stream>>>(x, Wp, bp, h);
  k_deg<<<(NE + 255) / 256, 256, 0, stream>>>(dst, deg);
  k_scan<<<1, 1024, 0, stream>>>(deg, rowptr);
  k_fill<<<(NE + 255) / 256, 256, 0, stream>>>(src, dst, rowptr, cursor, csr);

  int ggrid = 8 * 6 * ((NBAND + 7) / 8);  // 2352; decode in-kernel
  for (int l = 0; l < NL; ++l) {
    k_agg<<<NN, 192, 0, stream>>>(h, csr, rowptr, agg);
    k_gemm<<<ggrid, 256, 0, stream>>>(agg, h,
                                      Wlb + (size_t)l * HID * HID,
                                      Wrb + (size_t)l * HID * HID,
                                      bl + (size_t)l * HID, sact, NN);
    k_ln<<<NN, 256, 0, stream>>>(sact, gamma + (size_t)l * HID, beta + (size_t)l * HID,
                                 h, (l == NL - 1) ? out : nullptr);
  }
}